// Round 9
// baseline (377.138 us; speedup 1.0000x reference)
//
#include <hip/hip_runtime.h>

#define N_NODES 100000
#define N_EDGES 2000000

typedef __bf16 bf16x8 __attribute__((ext_vector_type(8)));
typedef float f32x4 __attribute__((ext_vector_type(4)));
typedef float f32x16 __attribute__((ext_vector_type(16)));

__device__ __forceinline__ unsigned f2bf_rne(float f) {
  unsigned u = __builtin_bit_cast(unsigned, f);
  u += 0x7FFFu + ((u >> 16) & 1u);
  return u >> 16;
}

// Pack two NON-NEGATIVE f32 into bf16x2, round-half-up.
__device__ __forceinline__ unsigned pack_rhu(float lo, float hi) {
  unsigned ulo = __builtin_bit_cast(unsigned, lo) + 0x8000u;
  unsigned uhi = __builtin_bit_cast(unsigned, hi) + 0x8000u;
  return __builtin_amdgcn_perm(uhi, ulo, 0x07060302u);
}

// |a-b| on a packed bf16 pair -> packed bf16 pair.
__device__ __forceinline__ unsigned absdiff_pack(unsigned a, unsigned b) {
  float alo = __builtin_bit_cast(float, a << 16);
  float ahi = __builtin_bit_cast(float, a & 0xFFFF0000u);
  float blo = __builtin_bit_cast(float, b << 16);
  float bhi = __builtin_bit_cast(float, b & 0xFFFF0000u);
  return pack_rhu(fabsf(alo - blo), fabsf(ahi - bhi));
}

// ---------------------------------------------------------------------------
// Node MLP via MFMA, grid-stride (round-4 version, proven; the residual
// total-minus-edge gap is fixed harness overhead).
// ---------------------------------------------------------------------------
__global__ __launch_bounds__(64, 1) void node_mfma_kernel(
    const float* __restrict__ X, const float* __restrict__ W1,
    const float* __restrict__ b1, const float* __restrict__ W2,
    const float* __restrict__ b2, unsigned short* __restrict__ H) {
  const int lane = threadIdx.x;
  const int l15 = lane & 15;
  const int quad = lane >> 4;

  float w1v[2][4][8], b1v[2][8];
#pragma unroll
  for (int c = 0; c < 2; ++c)
#pragma unroll
    for (int j = 0; j < 8; ++j) {
      int col = c * 32 + quad * 8 + j;
      b1v[c][j] = b1[col];
#pragma unroll
      for (int d = 0; d < 4; ++d) w1v[c][d][j] = W1[d * 64 + col];
    }

  uint4 afr[2][4];
#pragma unroll
  for (int c = 0; c < 2; ++c)
#pragma unroll
    for (int mt = 0; mt < 4; ++mt) {
      unsigned w[4];
#pragma unroll
      for (int p = 0; p < 4; ++p) {
        int k = c * 32 + quad * 8 + 2 * p;
        unsigned lo = f2bf_rne(W2[k * 64 + mt * 16 + l15]);
        unsigned hi = f2bf_rne(W2[(k + 1) * 64 + mt * 16 + l15]);
        w[p] = lo | (hi << 16);
      }
      afr[c][mt] = make_uint4(w[0], w[1], w[2], w[3]);
    }
  float b2v[16];
#pragma unroll
  for (int mt = 0; mt < 4; ++mt)
#pragma unroll
    for (int r = 0; r < 4; ++r) b2v[mt * 4 + r] = b2[mt * 16 + quad * 4 + r];

  const int ntiles = N_NODES / 16;  // 6250
  for (int tile = blockIdx.x; tile < ntiles; tile += gridDim.x) {
    float4 xv = ((const float4*)X)[tile * 16 + l15];

    uint4 bfr[2];
#pragma unroll
    for (int c = 0; c < 2; ++c) {
      unsigned w[4];
#pragma unroll
      for (int p = 0; p < 4; ++p) {
        float h0 = fmaxf(b1v[c][2 * p] + xv.x * w1v[c][0][2 * p] +
                             xv.y * w1v[c][1][2 * p] + xv.z * w1v[c][2][2 * p] +
                             xv.w * w1v[c][3][2 * p],
                         0.f);
        float h1 = fmaxf(b1v[c][2 * p + 1] + xv.x * w1v[c][0][2 * p + 1] +
                             xv.y * w1v[c][1][2 * p + 1] +
                             xv.z * w1v[c][2][2 * p + 1] +
                             xv.w * w1v[c][3][2 * p + 1],
                         0.f);
        w[p] = pack_rhu(h0, h1);
      }
      bfr[c] = make_uint4(w[0], w[1], w[2], w[3]);
    }

    f32x4 acc[4];
#pragma unroll
    for (int mt = 0; mt < 4; ++mt) acc[mt] = (f32x4){0.f, 0.f, 0.f, 0.f};
#pragma unroll
    for (int c = 0; c < 2; ++c)
#pragma unroll
      for (int mt = 0; mt < 4; ++mt)
        acc[mt] = __builtin_amdgcn_mfma_f32_16x16x32_bf16(
            __builtin_bit_cast(bf16x8, afr[c][mt]),
            __builtin_bit_cast(bf16x8, bfr[c]), acc[mt], 0, 0, 0);

    unsigned short* hrow = H + (tile * 16 + l15) * 64;
#pragma unroll
    for (int mt = 0; mt < 4; ++mt) {
      unsigned lo = pack_rhu(fmaxf(acc[mt][0] + b2v[mt * 4 + 0], 0.f),
                             fmaxf(acc[mt][1] + b2v[mt * 4 + 1], 0.f));
      unsigned hi = pack_rhu(fmaxf(acc[mt][2] + b2v[mt * 4 + 2], 0.f),
                             fmaxf(acc[mt][3] + b2v[mt * 4 + 3], 0.f));
      *(uint2*)(hrow + mt * 16 + quad * 4) = make_uint2(lo, hi);
    }
  }
}

// ---------------------------------------------------------------------------
// Edge MLP with 32x32x16 MFMA (round-8 kernel, UNCHANGED except launch
// bounds): one wave = 32 edges/tile. Round-8 measured VGPR_Count=128 arch +
// 32 acc = 160/wave unconstrained — which already fits 3 waves/SIMD
// (512/3=170). (256,2) let the allocator settle into a 2-wave layout and the
// SIMD issue pipes sat 60% idle (MFMA 832 + VALU ~600 of 3690 cyc/tile).
// (256,3) + grid 768 (exactly 3 blocks/CU) raises TLP with the same
// per-tile work. Spill tripwire: WRITE_SIZE must stay ~7.8MB.
// ---------------------------------------------------------------------------
__global__ __launch_bounds__(256, 3) void edge_mlp_kernel(
    const unsigned short* __restrict__ H, const int* __restrict__ pairs,
    const float* __restrict__ We1, const float* __restrict__ be1,
    const float* __restrict__ We2, const float* __restrict__ be2,
    float* __restrict__ out) {
  __shared__ uint4 wlds[26 * 64];  // 26 KB
  const int tid = threadIdx.x;

  // Stage A-frags: frag f=c*2+mt, lane ln, elem j:
  //   c<12 : We1[(c*16+(ln>>5)*8+j)*64 + mt*32+(ln&31)]
  //   c==12: j==0 && (ln>>5)==0 ? be1[mt*32+(ln&31)] : 0
  for (int s = tid; s < 26 * 64; s += 256) {
    int f = s >> 6, ln = s & 63;
    int c = f >> 1, mt = f & 1;
    int col = mt * 32 + (ln & 31);
    uint4 val;
    if (c < 12) {
      int kb = c * 16 + (ln >> 5) * 8;
      val.x = f2bf_rne(We1[(kb + 0) * 64 + col]) |
              (f2bf_rne(We1[(kb + 1) * 64 + col]) << 16);
      val.y = f2bf_rne(We1[(kb + 2) * 64 + col]) |
              (f2bf_rne(We1[(kb + 3) * 64 + col]) << 16);
      val.z = f2bf_rne(We1[(kb + 4) * 64 + col]) |
              (f2bf_rne(We1[(kb + 5) * 64 + col]) << 16);
      val.w = f2bf_rne(We1[(kb + 6) * 64 + col]) |
              (f2bf_rne(We1[(kb + 7) * 64 + col]) << 16);
    } else {
      val.x = ((ln >> 5) == 0) ? f2bf_rne(be1[col]) : 0u;
      val.y = 0u;
      val.z = 0u;
      val.w = 0u;
    }
    wlds[s] = val;
  }

  const int lane = tid & 63;
  const int n = lane & 31;   // edge within tile
  const int half = lane >> 5;

  // B-frag for the bias chunk: B13[0][n]=1.0 -> half==0, j==0 elem = 1.0bf16.
  uint4 b13u = make_uint4((half == 0) ? 0x00003F80u : 0u, 0u, 0u, 0u);

  // We2 per-lane constants: row = mt*32 + (r&3)+8*(r>>2)+4*half.
  float we2v[32];
#pragma unroll
  for (int mt = 0; mt < 2; ++mt)
#pragma unroll
    for (int r = 0; r < 16; ++r)
      we2v[mt * 16 + r] = We2[mt * 32 + (r & 3) + 8 * (r >> 2) + 4 * half];
  const float be2v = be2[0];
  __syncthreads();

  const int wid = blockIdx.x * 4 + (tid >> 6);
  const int nw = gridDim.x * 4;
  const int ntiles = N_EDGES / 32;  // 62500
  const int last = ntiles - 1;
  const int2* pairs2 = (const int2*)pairs;
  const uint4* wf = wlds + lane;  // frag f at wf[f*64]

  // Double-buffered gathers: hu chunks 0-3 + hv chunks 0-3 per buffer.
  uint4 g[2][8];
  int2 uvn[2];
#pragma unroll
  for (int k = 0; k < 2; ++k) {
    int t = wid + k * nw;
    t = (t <= last) ? t : last;
    int2 uv = pairs2[t * 32 + n];
    const uint4* pu = (const uint4*)(H + uv.x * 64 + half * 8);
    const uint4* pv = (const uint4*)(H + uv.y * 64 + half * 8);
#pragma unroll
    for (int c = 0; c < 4; ++c) {
      g[k][c] = pu[c * 2];
      g[k][4 + c] = pv[c * 2];
    }
    int tn = wid + (k + 2) * nw;
    tn = (tn <= last) ? tn : last;
    uvn[k] = pairs2[tn * 32 + n];
  }

  for (int base = wid; base < ntiles; base += 2 * nw) {
#pragma unroll
    for (int k = 0; k < 2; ++k) {
      int t = base + k * nw;
      t = (t <= last) ? t : last;  // tail: recompute last tile (same value)

      // |hu-hv| chunks (k 128..191 of E).
      uint4 ab[4];
#pragma unroll
      for (int c = 0; c < 4; ++c) {
        ab[c].x = absdiff_pack(g[k][c].x, g[k][4 + c].x);
        ab[c].y = absdiff_pack(g[k][c].y, g[k][4 + c].y);
        ab[c].z = absdiff_pack(g[k][c].z, g[k][4 + c].z);
        ab[c].w = absdiff_pack(g[k][c].w, g[k][4 + c].w);
      }

      f32x16 acc[2];
      acc[0] = (f32x16)(0.f);
      acc[1] = (f32x16)(0.f);
#pragma unroll
      for (int c = 0; c < 13; ++c) {
        uint4 bu = (c < 8) ? g[k][c] : (c < 12 ? ab[c - 8] : b13u);
        bf16x8 b = __builtin_bit_cast(bf16x8, bu);
#pragma unroll
        for (int mt = 0; mt < 2; ++mt) {
          bf16x8 a = __builtin_bit_cast(bf16x8, wf[(c * 2 + mt) * 64]);
          acc[mt] = __builtin_amdgcn_mfma_f32_32x32x16_bf16(a, b, acc[mt], 0,
                                                            0, 0);
        }
      }

      // Refill buffer k for tile t+2nw (WAR only, no wait).
      {
        const uint4* qu = (const uint4*)(H + uvn[k].x * 64 + half * 8);
        const uint4* qv = (const uint4*)(H + uvn[k].y * 64 + half * 8);
#pragma unroll
        for (int c = 0; c < 4; ++c) {
          g[k][c] = qu[c * 2];
          g[k][4 + c] = qv[c * 2];
        }
        int tn = base + (k + 4) * nw;
        tn = (tn <= last) ? tn : last;
        uvn[k] = pairs2[tn * 32 + n];
      }

      // Epilogue: bias already in acc via chunk 12 -> relu(acc)*We2, sum
      // over this lane's 32 rows, combine the two half-wave partials.
      float s = 0.f;
#pragma unroll
      for (int mt = 0; mt < 2; ++mt)
#pragma unroll
        for (int r = 0; r < 16; ++r)
          s += fmaxf(acc[mt][r], 0.f) * we2v[mt * 16 + r];
      s += __shfl_xor(s, 32);
      if (half == 0) out[t * 32 + n] = s + be2v;
    }
  }
}

extern "C" void kernel_launch(void* const* d_in, const int* in_sizes, int n_in,
                              void* d_out, int out_size, void* d_ws,
                              size_t ws_size, hipStream_t stream) {
  const float* X = (const float*)d_in[0];
  const int* pairs = (const int*)d_in[1];
  const float* W1 = (const float*)d_in[2];
  const float* b1 = (const float*)d_in[3];
  const float* W2 = (const float*)d_in[4];
  const float* b2 = (const float*)d_in[5];
  const float* We1 = (const float*)d_in[6];
  const float* be1 = (const float*)d_in[7];
  const float* We2 = (const float*)d_in[8];
  const float* be2 = (const float*)d_in[9];
  float* out = (float*)d_out;
  unsigned short* H = (unsigned short*)d_ws;  // 100000*64 bf16 = 12.8 MB

  node_mfma_kernel<<<1024, 64, 0, stream>>>(X, W1, b1, W2, b2, H);
  // 768 = 3 blocks/CU x 256 CU: exact co-residency at 3 waves/SIMD.
  edge_mlp_kernel<<<768, 256, 0, stream>>>(H, pairs, We1, be1, We2, be2, out);
}

// Round 10
// 164.447 us; speedup vs baseline: 2.2934x; 2.2934x over previous
//
#include <hip/hip_runtime.h>

#define N_NODES 100000
#define N_EDGES 2000000

typedef __bf16 bf16x8 __attribute__((ext_vector_type(8)));
typedef float f32x4 __attribute__((ext_vector_type(4)));
typedef float f32x16 __attribute__((ext_vector_type(16)));

#define AS1 __attribute__((address_space(1)))
#define AS3 __attribute__((address_space(3)))

__device__ __forceinline__ unsigned f2bf_rne(float f) {
  unsigned u = __builtin_bit_cast(unsigned, f);
  u += 0x7FFFu + ((u >> 16) & 1u);
  return u >> 16;
}

// Pack two NON-NEGATIVE f32 into bf16x2, round-half-up.
__device__ __forceinline__ unsigned pack_rhu(float lo, float hi) {
  unsigned ulo = __builtin_bit_cast(unsigned, lo) + 0x8000u;
  unsigned uhi = __builtin_bit_cast(unsigned, hi) + 0x8000u;
  return __builtin_amdgcn_perm(uhi, ulo, 0x07060302u);
}

// |a-b| on a packed bf16 pair -> packed bf16 pair.
__device__ __forceinline__ unsigned absdiff_pack(unsigned a, unsigned b) {
  float alo = __builtin_bit_cast(float, a << 16);
  float ahi = __builtin_bit_cast(float, a & 0xFFFF0000u);
  float blo = __builtin_bit_cast(float, b << 16);
  float bhi = __builtin_bit_cast(float, b & 0xFFFF0000u);
  return pack_rhu(fabsf(alo - blo), fabsf(ahi - bhi));
}

// ---------------------------------------------------------------------------
// Node MLP via MFMA, grid-stride (round-4 version, proven; the residual
// total-minus-edge gap is fixed harness overhead).
// ---------------------------------------------------------------------------
__global__ __launch_bounds__(64, 1) void node_mfma_kernel(
    const float* __restrict__ X, const float* __restrict__ W1,
    const float* __restrict__ b1, const float* __restrict__ W2,
    const float* __restrict__ b2, unsigned short* __restrict__ H) {
  const int lane = threadIdx.x;
  const int l15 = lane & 15;
  const int quad = lane >> 4;

  float w1v[2][4][8], b1v[2][8];
#pragma unroll
  for (int c = 0; c < 2; ++c)
#pragma unroll
    for (int j = 0; j < 8; ++j) {
      int col = c * 32 + quad * 8 + j;
      b1v[c][j] = b1[col];
#pragma unroll
      for (int d = 0; d < 4; ++d) w1v[c][d][j] = W1[d * 64 + col];
    }

  uint4 afr[2][4];
#pragma unroll
  for (int c = 0; c < 2; ++c)
#pragma unroll
    for (int mt = 0; mt < 4; ++mt) {
      unsigned w[4];
#pragma unroll
      for (int p = 0; p < 4; ++p) {
        int k = c * 32 + quad * 8 + 2 * p;
        unsigned lo = f2bf_rne(W2[k * 64 + mt * 16 + l15]);
        unsigned hi = f2bf_rne(W2[(k + 1) * 64 + mt * 16 + l15]);
        w[p] = lo | (hi << 16);
      }
      afr[c][mt] = make_uint4(w[0], w[1], w[2], w[3]);
    }
  float b2v[16];
#pragma unroll
  for (int mt = 0; mt < 4; ++mt)
#pragma unroll
    for (int r = 0; r < 4; ++r) b2v[mt * 4 + r] = b2[mt * 16 + quad * 4 + r];

  const int ntiles = N_NODES / 16;  // 6250
  for (int tile = blockIdx.x; tile < ntiles; tile += gridDim.x) {
    float4 xv = ((const float4*)X)[tile * 16 + l15];

    uint4 bfr[2];
#pragma unroll
    for (int c = 0; c < 2; ++c) {
      unsigned w[4];
#pragma unroll
      for (int p = 0; p < 4; ++p) {
        float h0 = fmaxf(b1v[c][2 * p] + xv.x * w1v[c][0][2 * p] +
                             xv.y * w1v[c][1][2 * p] + xv.z * w1v[c][2][2 * p] +
                             xv.w * w1v[c][3][2 * p],
                         0.f);
        float h1 = fmaxf(b1v[c][2 * p + 1] + xv.x * w1v[c][0][2 * p + 1] +
                             xv.y * w1v[c][1][2 * p + 1] +
                             xv.z * w1v[c][2][2 * p + 1] +
                             xv.w * w1v[c][3][2 * p + 1],
                         0.f);
        w[p] = pack_rhu(h0, h1);
      }
      bfr[c] = make_uint4(w[0], w[1], w[2], w[3]);
    }

    f32x4 acc[4];
#pragma unroll
    for (int mt = 0; mt < 4; ++mt) acc[mt] = (f32x4){0.f, 0.f, 0.f, 0.f};
#pragma unroll
    for (int c = 0; c < 2; ++c)
#pragma unroll
      for (int mt = 0; mt < 4; ++mt)
        acc[mt] = __builtin_amdgcn_mfma_f32_16x16x32_bf16(
            __builtin_bit_cast(bf16x8, afr[c][mt]),
            __builtin_bit_cast(bf16x8, bfr[c]), acc[mt], 0, 0, 0);

    unsigned short* hrow = H + (tile * 16 + l15) * 64;
#pragma unroll
    for (int mt = 0; mt < 4; ++mt) {
      unsigned lo = pack_rhu(fmaxf(acc[mt][0] + b2v[mt * 4 + 0], 0.f),
                             fmaxf(acc[mt][1] + b2v[mt * 4 + 1], 0.f));
      unsigned hi = pack_rhu(fmaxf(acc[mt][2] + b2v[mt * 4 + 2], 0.f),
                             fmaxf(acc[mt][3] + b2v[mt * 4 + 3], 0.f));
      *(uint2*)(hrow + mt * 16 + quad * 4) = make_uint2(lo, hi);
    }
  }
}

// ---------------------------------------------------------------------------
// Edge MLP, 32x32x16 MFMA + LDS-staged gathers via global_load_lds.
// Per 32-edge tile, the 64 needed H rows (hu 32 + hv 32) are fetched with 8
// global_load_lds_dwordx4 instructions where 8 CONSECUTIVE lanes cover one
// 128B row -> rows fetch as full cache lines (~128 L2 requests/tile vs ~256
// for the old per-lane-scattered layout; rounds 3-9 were pinned at 93-103us
// by L2 request rate, invariant to pipelining and occupancy). Gather VGPRs
// drop to ZERO (LDS holds the rows; no spill risk at any launch bound).
// XOR swizzle: lane fetches global chunk (l&7)^(l>>3) so row r stores chunk
// ch at position ch^(r&7) -> readback ds_read_b128 is <=4-way conflicted.
// Readback: lane l reads row l&31 chunks 2c+(l>>5) (its MFMA B k-slice).
// Per-wave 8KB buffer, no barriers (same-wave vmcnt/lgkmcnt fences only).
// LDS: 26KB weights + 4x8KB = 58KB -> 2 blocks/CU.
// ---------------------------------------------------------------------------
__global__ __launch_bounds__(256, 2) void edge_mlp_kernel(
    const unsigned short* __restrict__ H, const int* __restrict__ pairs,
    const float* __restrict__ We1, const float* __restrict__ be1,
    const float* __restrict__ We2, const float* __restrict__ be2,
    float* __restrict__ out) {
  __shared__ uint4 wlds[26 * 64];   // 26 KB weight A-frags
  __shared__ uint4 gbuf[4 * 512];   // 4 waves x 8 KB row staging
  const int tid = threadIdx.x;

  // Stage A-frags (identical to round 8, numerically verified):
  for (int s = tid; s < 26 * 64; s += 256) {
    int f = s >> 6, ln = s & 63;
    int c = f >> 1, mt = f & 1;
    int col = mt * 32 + (ln & 31);
    uint4 val;
    if (c < 12) {
      int kb = c * 16 + (ln >> 5) * 8;
      val.x = f2bf_rne(We1[(kb + 0) * 64 + col]) |
              (f2bf_rne(We1[(kb + 1) * 64 + col]) << 16);
      val.y = f2bf_rne(We1[(kb + 2) * 64 + col]) |
              (f2bf_rne(We1[(kb + 3) * 64 + col]) << 16);
      val.z = f2bf_rne(We1[(kb + 4) * 64 + col]) |
              (f2bf_rne(We1[(kb + 5) * 64 + col]) << 16);
      val.w = f2bf_rne(We1[(kb + 6) * 64 + col]) |
              (f2bf_rne(We1[(kb + 7) * 64 + col]) << 16);
    } else {
      val.x = ((ln >> 5) == 0) ? f2bf_rne(be1[col]) : 0u;
      val.y = 0u;
      val.z = 0u;
      val.w = 0u;
    }
    wlds[s] = val;
  }

  const int lane = tid & 63;
  const int n = lane & 31;        // edge within tile (readback role)
  const int half = lane >> 5;     // k-half (readback role)
  const int wave = tid >> 6;
  const int rowsel = lane >> 3;   // 0..7: row within group (loader role)
  const int swzc = (lane & 7) ^ rowsel;  // global 16B chunk to fetch

  uint4* gw = &gbuf[wave * 512];  // this wave's 8KB: [hu 32 rows][hv 32 rows]

  // B-frag for the bias chunk: B13[0][n]=1.0.
  uint4 b13u = make_uint4((half == 0) ? 0x00003F80u : 0u, 0u, 0u, 0u);

  // We2 per-lane constants: row = mt*32 + (r&3)+8*(r>>2)+4*half.
  float we2v[32];
#pragma unroll
  for (int mt = 0; mt < 2; ++mt)
#pragma unroll
    for (int r = 0; r < 16; ++r)
      we2v[mt * 16 + r] = We2[mt * 32 + (r & 3) + 8 * (r >> 2) + 4 * half];
  const float be2v = be2[0];
  __syncthreads();

  // Readback pointers: hu chunk c at gw[n*8 + ((2c+half)^(n&7))], hv +256.
  const uint4* rb[4];
#pragma unroll
  for (int c = 0; c < 4; ++c) rb[c] = gw + n * 8 + (((2 * c + half) ^ (n & 7)));

  const int wid = blockIdx.x * 4 + wave;
  const int nw = gridDim.x * 4;
  const int ntiles = N_EDGES / 32;  // 62500
  const int last = ntiles - 1;
  const int2* pairs2 = (const int2*)pairs;

  // Issue row-group gathers for tile t: group k covers rows k*8+rowsel.
  auto issue_gathers = [&](int2 pr0, int2 pr1, int2 pr2, int2 pr3) {
    int2 prs[4] = {pr0, pr1, pr2, pr3};
#pragma unroll
    for (int k = 0; k < 4; ++k) {
      const AS1 unsigned* gu =
          (const AS1 unsigned*)(H + (size_t)prs[k].x * 64) + swzc * 4;
      const AS1 unsigned* gv =
          (const AS1 unsigned*)(H + (size_t)prs[k].y * 64) + swzc * 4;
      __builtin_amdgcn_global_load_lds(gu, (AS3 unsigned*)(gw + k * 64), 16, 0,
                                       0);
      __builtin_amdgcn_global_load_lds(gv,
                                       (AS3 unsigned*)(gw + 256 + k * 64), 16,
                                       0, 0);
    }
  };

  // Prologue: issue gathers for first tile; prefetch pairs for second.
  int2 pr[4];
  {
    int t0 = wid;  // wid < ntiles always (nw=4096 << 62500)
#pragma unroll
    for (int k = 0; k < 4; ++k) pr[k] = pairs2[t0 * 32 + k * 8 + rowsel];
    issue_gathers(pr[0], pr[1], pr[2], pr[3]);
    int t1 = wid + nw <= last ? wid + nw : last;
#pragma unroll
    for (int k = 0; k < 4; ++k) pr[k] = pairs2[t1 * 32 + k * 8 + rowsel];
  }

  for (int tile = wid; tile < ntiles; tile += nw) {
    // Wait for this tile's rows to land in LDS (per-wave, no barrier).
    __builtin_amdgcn_s_waitcnt(0x0F70);  // vmcnt(0)
    __builtin_amdgcn_sched_barrier(0);

    // Read back MFMA B-fragments.
    uint4 hu[4], hv[4];
#pragma unroll
    for (int c = 0; c < 4; ++c) {
      hu[c] = rb[c][0];
      hv[c] = rb[c][256];
    }

    uint4 ab[4];
#pragma unroll
    for (int c = 0; c < 4; ++c) {
      ab[c].x = absdiff_pack(hu[c].x, hv[c].x);
      ab[c].y = absdiff_pack(hu[c].y, hv[c].y);
      ab[c].z = absdiff_pack(hu[c].z, hv[c].z);
      ab[c].w = absdiff_pack(hu[c].w, hv[c].w);
    }

    f32x16 acc[2];
    acc[0] = (f32x16)(0.f);
    acc[1] = (f32x16)(0.f);
    const uint4* wf = wlds + lane;
#pragma unroll
    for (int c = 0; c < 13; ++c) {
      uint4 bu = (c < 4) ? hu[c]
                         : (c < 8) ? hv[c - 4] : (c < 12 ? ab[c - 8] : b13u);
      bf16x8 b = __builtin_bit_cast(bf16x8, bu);
#pragma unroll
      for (int mt = 0; mt < 2; ++mt) {
        bf16x8 a = __builtin_bit_cast(bf16x8, wf[(c * 2 + mt) * 64]);
        acc[mt] =
            __builtin_amdgcn_mfma_f32_32x32x16_bf16(a, b, acc[mt], 0, 0, 0);
      }
    }

    // All ds_reads (gather + weights) must finish before refilling gbuf.
    __builtin_amdgcn_s_waitcnt(0xC07F);  // lgkmcnt(0)
    __builtin_amdgcn_sched_barrier(0);

    // Issue next tile's gathers; prefetch pairs for tile+2nw.
    issue_gathers(pr[0], pr[1], pr[2], pr[3]);
    {
      int t2 = tile + 2 * nw <= last ? tile + 2 * nw : last;
#pragma unroll
      for (int k = 0; k < 4; ++k) pr[k] = pairs2[t2 * 32 + k * 8 + rowsel];
    }

    // Epilogue (independent of the refill): relu(acc)*We2, half-wave reduce.
    float s = 0.f;
#pragma unroll
    for (int mt = 0; mt < 2; ++mt)
#pragma unroll
      for (int r = 0; r < 16; ++r)
        s += fmaxf(acc[mt][r], 0.f) * we2v[mt * 16 + r];
    s += __shfl_xor(s, 32);
    if (half == 0) out[tile * 32 + n] = s + be2v;
  }
}

extern "C" void kernel_launch(void* const* d_in, const int* in_sizes, int n_in,
                              void* d_out, int out_size, void* d_ws,
                              size_t ws_size, hipStream_t stream) {
  const float* X = (const float*)d_in[0];
  const int* pairs = (const int*)d_in[1];
  const float* W1 = (const float*)d_in[2];
  const float* b1 = (const float*)d_in[3];
  const float* W2 = (const float*)d_in[4];
  const float* b2 = (const float*)d_in[5];
  const float* We1 = (const float*)d_in[6];
  const float* be1 = (const float*)d_in[7];
  const float* We2 = (const float*)d_in[8];
  const float* be2 = (const float*)d_in[9];
  float* out = (float*)d_out;
  unsigned short* H = (unsigned short*)d_ws;  // 100000*64 bf16 = 12.8 MB

  node_mfma_kernel<<<1024, 64, 0, stream>>>(X, W1, b1, W2, b2, H);
  // 512 = 2 blocks/CU (58 KB LDS each) — exact co-residency, 8 waves/CU.
  edge_mlp_kernel<<<512, 256, 0, stream>>>(H, pairs, We1, be1, We2, be2, out);
}

// Round 11
// 159.557 us; speedup vs baseline: 2.3637x; 1.0306x over previous
//
#include <hip/hip_runtime.h>

#define N_NODES 100000
#define N_EDGES 2000000

typedef __bf16 bf16x8 __attribute__((ext_vector_type(8)));
typedef float f32x4 __attribute__((ext_vector_type(4)));
typedef float f32x16 __attribute__((ext_vector_type(16)));

#define AS1 __attribute__((address_space(1)))
#define AS3 __attribute__((address_space(3)))

__device__ __forceinline__ unsigned f2bf_rne(float f) {
  unsigned u = __builtin_bit_cast(unsigned, f);
  u += 0x7FFFu + ((u >> 16) & 1u);
  return u >> 16;
}

// Pack two NON-NEGATIVE f32 into bf16x2, round-half-up.
__device__ __forceinline__ unsigned pack_rhu(float lo, float hi) {
  unsigned ulo = __builtin_bit_cast(unsigned, lo) + 0x8000u;
  unsigned uhi = __builtin_bit_cast(unsigned, hi) + 0x8000u;
  return __builtin_amdgcn_perm(uhi, ulo, 0x07060302u);
}

// |a-b| on a packed bf16 pair -> packed bf16 pair.
__device__ __forceinline__ unsigned absdiff_pack(unsigned a, unsigned b) {
  float alo = __builtin_bit_cast(float, a << 16);
  float ahi = __builtin_bit_cast(float, a & 0xFFFF0000u);
  float blo = __builtin_bit_cast(float, b << 16);
  float bhi = __builtin_bit_cast(float, b & 0xFFFF0000u);
  return pack_rhu(fabsf(alo - blo), fabsf(ahi - bhi));
}

// ---------------------------------------------------------------------------
// Node MLP via MFMA, grid-stride (round-4 version, proven; the residual
// total-minus-edge gap is fixed harness overhead).
// ---------------------------------------------------------------------------
__global__ __launch_bounds__(64, 1) void node_mfma_kernel(
    const float* __restrict__ X, const float* __restrict__ W1,
    const float* __restrict__ b1, const float* __restrict__ W2,
    const float* __restrict__ b2, unsigned short* __restrict__ H) {
  const int lane = threadIdx.x;
  const int l15 = lane & 15;
  const int quad = lane >> 4;

  float w1v[2][4][8], b1v[2][8];
#pragma unroll
  for (int c = 0; c < 2; ++c)
#pragma unroll
    for (int j = 0; j < 8; ++j) {
      int col = c * 32 + quad * 8 + j;
      b1v[c][j] = b1[col];
#pragma unroll
      for (int d = 0; d < 4; ++d) w1v[c][d][j] = W1[d * 64 + col];
    }

  uint4 afr[2][4];
#pragma unroll
  for (int c = 0; c < 2; ++c)
#pragma unroll
    for (int mt = 0; mt < 4; ++mt) {
      unsigned w[4];
#pragma unroll
      for (int p = 0; p < 4; ++p) {
        int k = c * 32 + quad * 8 + 2 * p;
        unsigned lo = f2bf_rne(W2[k * 64 + mt * 16 + l15]);
        unsigned hi = f2bf_rne(W2[(k + 1) * 64 + mt * 16 + l15]);
        w[p] = lo | (hi << 16);
      }
      afr[c][mt] = make_uint4(w[0], w[1], w[2], w[3]);
    }
  float b2v[16];
#pragma unroll
  for (int mt = 0; mt < 4; ++mt)
#pragma unroll
    for (int r = 0; r < 4; ++r) b2v[mt * 4 + r] = b2[mt * 16 + quad * 4 + r];

  const int ntiles = N_NODES / 16;  // 6250
  for (int tile = blockIdx.x; tile < ntiles; tile += gridDim.x) {
    float4 xv = ((const float4*)X)[tile * 16 + l15];

    uint4 bfr[2];
#pragma unroll
    for (int c = 0; c < 2; ++c) {
      unsigned w[4];
#pragma unroll
      for (int p = 0; p < 4; ++p) {
        float h0 = fmaxf(b1v[c][2 * p] + xv.x * w1v[c][0][2 * p] +
                             xv.y * w1v[c][1][2 * p] + xv.z * w1v[c][2][2 * p] +
                             xv.w * w1v[c][3][2 * p],
                         0.f);
        float h1 = fmaxf(b1v[c][2 * p + 1] + xv.x * w1v[c][0][2 * p + 1] +
                             xv.y * w1v[c][1][2 * p + 1] +
                             xv.z * w1v[c][2][2 * p + 1] +
                             xv.w * w1v[c][3][2 * p + 1],
                         0.f);
        w[p] = pack_rhu(h0, h1);
      }
      bfr[c] = make_uint4(w[0], w[1], w[2], w[3]);
    }

    f32x4 acc[4];
#pragma unroll
    for (int mt = 0; mt < 4; ++mt) acc[mt] = (f32x4){0.f, 0.f, 0.f, 0.f};
#pragma unroll
    for (int c = 0; c < 2; ++c)
#pragma unroll
      for (int mt = 0; mt < 4; ++mt)
        acc[mt] = __builtin_amdgcn_mfma_f32_16x16x32_bf16(
            __builtin_bit_cast(bf16x8, afr[c][mt]),
            __builtin_bit_cast(bf16x8, bfr[c]), acc[mt], 0, 0, 0);

    unsigned short* hrow = H + (tile * 16 + l15) * 64;
#pragma unroll
    for (int mt = 0; mt < 4; ++mt) {
      unsigned lo = pack_rhu(fmaxf(acc[mt][0] + b2v[mt * 4 + 0], 0.f),
                             fmaxf(acc[mt][1] + b2v[mt * 4 + 1], 0.f));
      unsigned hi = pack_rhu(fmaxf(acc[mt][2] + b2v[mt * 4 + 2], 0.f),
                             fmaxf(acc[mt][3] + b2v[mt * 4 + 3], 0.f));
      *(uint2*)(hrow + mt * 16 + quad * 4) = make_uint2(lo, hi);
    }
  }
}

// ---------------------------------------------------------------------------
// Edge MLP: 32x32x16 MFMA + DOUBLE-BUFFERED LDS row staging.
// r10 (single-buffer, vmcnt(0)) exposed the full gather latency each tile
// (~1600 idle cyc of 3150). Now: two statically-distinct 8KB buffers per
// wave; the refill for tile t+1 is issued into the other buffer right after
// the top-of-loop wait, one full tile-compute before consumption. The wait
// is a partial s_waitcnt vmcnt(5): after each tile's 8 gather-loads, exactly
// 4 pairs-loads + 1 store follow in vmem order (sched_barrier pins gathers
// before pairs; a 1-op prologue dummy makes iter 0 consistent; older
// outstanding ops only make the wait stricter, never unsafe).
// We1^T A-frags move back to REGISTERS (104 regs; arch ~113 + agpr 136 =
// 249 <= 256 at (256,2) -> no spill) because LDS is spent on the dbuf:
// 4 waves x 2 x 8KB + 1KB pad = 65KB -> 2 blocks/CU, 2 waves/SIMD. Also
// removes 26 ds_read_b128/tile of weight traffic.
// ---------------------------------------------------------------------------
__global__ __launch_bounds__(256, 2) void edge_mlp_kernel(
    const unsigned short* __restrict__ H, const int* __restrict__ pairs,
    const float* __restrict__ We1, const float* __restrict__ be1,
    const float* __restrict__ We2, const float* __restrict__ be2,
    float* __restrict__ out) {
  __shared__ uint4 gbuf[4][2][512];  // [wave][buf][rows]: 64 KB
  __shared__ uint4 scratch[64];      // 1 KB dummy-gather landing pad
  const int tid = threadIdx.x;
  const int lane = tid & 63;
  const int n = lane & 31;       // edge within tile (readback role)
  const int half = lane >> 5;    // k-half (readback role)
  const int wave = tid >> 6;
  const int rowsel = lane >> 3;  // loader role: row within 8-row group
  const int swzc = (lane & 7) ^ rowsel;  // global 16B chunk to fetch

  // We1^T A-frags in registers: afr[c][mt] elem j =
  //   c<12 : We1[(c*16+half*8+j)*64 + mt*32+n]   (bf16 RNE packed)
  //   c==12: bias chunk A13[:,0]=be1 -> elem0 = be1[col] if half==0
  uint4 afr[13][2];
#pragma unroll
  for (int c = 0; c < 12; ++c)
#pragma unroll
    for (int mt = 0; mt < 2; ++mt) {
      int col = mt * 32 + n;
      int kb = c * 16 + half * 8;
      unsigned w[4];
#pragma unroll
      for (int p = 0; p < 4; ++p)
        w[p] = f2bf_rne(We1[(kb + 2 * p) * 64 + col]) |
               (f2bf_rne(We1[(kb + 2 * p + 1) * 64 + col]) << 16);
      afr[c][mt] = make_uint4(w[0], w[1], w[2], w[3]);
    }
#pragma unroll
  for (int mt = 0; mt < 2; ++mt)
    afr[12][mt] =
        make_uint4((half == 0) ? f2bf_rne(be1[mt * 32 + n]) : 0u, 0u, 0u, 0u);

  // B-frag for the bias chunk: B13[0][n]=1.0.
  const uint4 b13u = make_uint4((half == 0) ? 0x00003F80u : 0u, 0u, 0u, 0u);

  // We2 per-lane constants: row = mt*32 + (r&3)+8*(r>>2)+4*half.
  float we2v[32];
#pragma unroll
  for (int mt = 0; mt < 2; ++mt)
#pragma unroll
    for (int r = 0; r < 16; ++r)
      we2v[mt * 16 + r] = We2[mt * 32 + (r & 3) + 8 * (r >> 2) + 4 * half];
  const float be2v = be2[0];

  uint4* const bufA = &gbuf[wave][0][0];
  uint4* const bufB = &gbuf[wave][1][0];
  int rbo[4];
#pragma unroll
  for (int c = 0; c < 4; ++c) rbo[c] = n * 8 + ((2 * c + half) ^ (n & 7));

  const int wid = blockIdx.x * 4 + wave;
  const int nw = gridDim.x * 4;  // 2048
  const int ntiles = N_EDGES / 32;
  const int last = ntiles - 1;
  const int2* pairs2 = (const int2*)pairs;

  // Issue the 8 row-group gathers for one tile into buffer `dst`.
  auto issue_gathers = [&](uint4* dst, const int2* prs) {
#pragma unroll
    for (int k = 0; k < 4; ++k) {
      const AS1 unsigned* gu =
          (const AS1 unsigned*)(H + (size_t)prs[k].x * 64) + swzc * 4;
      const AS1 unsigned* gv =
          (const AS1 unsigned*)(H + (size_t)prs[k].y * 64) + swzc * 4;
      __builtin_amdgcn_global_load_lds(gu, (AS3 unsigned*)(dst + k * 64), 16,
                                       0, 0);
      __builtin_amdgcn_global_load_lds(
          gv, (AS3 unsigned*)(dst + 256 + k * 64), 16, 0, 0);
    }
  };

  // Prologue: gathers(t0)->A [8]; pr=pairs(t1) [4]; dummy [1] => 13
  // outstanding, so iter0's vmcnt(5) retires exactly the 8 t0-gathers.
  int2 pr[4];
  {
#pragma unroll
    for (int k = 0; k < 4; ++k) pr[k] = pairs2[wid * 32 + k * 8 + rowsel];
    issue_gathers(bufA, pr);
    int t1 = wid + nw <= last ? wid + nw : last;
#pragma unroll
    for (int k = 0; k < 4; ++k) pr[k] = pairs2[t1 * 32 + k * 8 + rowsel];
    __builtin_amdgcn_global_load_lds((const AS1 unsigned*)H,
                                     (AS3 unsigned*)scratch, 16, 0, 0);
  }

  // One tile: consume CONS (tile tc), refill FILL (tile tc+nw, pairs in pr),
  // reload pr for tile tc+2nw, epilogue store.
  auto body = [&](int tc, uint4* CONS, uint4* FILL) {
    __builtin_amdgcn_sched_barrier(0);
    __builtin_amdgcn_s_waitcnt(0x0F75);  // vmcnt(5): this tile's rows landed
    __builtin_amdgcn_sched_barrier(0);

    issue_gathers(FILL, pr);  // tile tc+nw, one full compute ahead of use
    __builtin_amdgcn_sched_barrier(0);  // pin: gathers before pairs loads
    {
      int tn = tc + 2 * nw <= last ? tc + 2 * nw : last;
#pragma unroll
      for (int k = 0; k < 4; ++k) pr[k] = pairs2[tn * 32 + k * 8 + rowsel];
    }

    const int t = tc <= last ? tc : last;  // tail: recompute last (idempotent)
    uint4 hu[4], hv[4];
#pragma unroll
    for (int c = 0; c < 4; ++c) {
      hu[c] = CONS[rbo[c]];
      hv[c] = CONS[256 + rbo[c]];
    }
    uint4 ab[4];
#pragma unroll
    for (int c = 0; c < 4; ++c) {
      ab[c].x = absdiff_pack(hu[c].x, hv[c].x);
      ab[c].y = absdiff_pack(hu[c].y, hv[c].y);
      ab[c].z = absdiff_pack(hu[c].z, hv[c].z);
      ab[c].w = absdiff_pack(hu[c].w, hv[c].w);
    }

    f32x16 acc[2];
    acc[0] = (f32x16)(0.f);
    acc[1] = (f32x16)(0.f);
#pragma unroll
    for (int c = 0; c < 13; ++c) {
      uint4 bu = (c < 4) ? hu[c]
                         : (c < 8) ? hv[c - 4] : (c < 12 ? ab[c - 8] : b13u);
      bf16x8 b = __builtin_bit_cast(bf16x8, bu);
#pragma unroll
      for (int mt = 0; mt < 2; ++mt)
        acc[mt] = __builtin_amdgcn_mfma_f32_32x32x16_bf16(
            __builtin_bit_cast(bf16x8, afr[c][mt]), b, acc[mt], 0, 0, 0);
    }

    float s = 0.f;
#pragma unroll
    for (int mt = 0; mt < 2; ++mt)
#pragma unroll
      for (int r = 0; r < 16; ++r)
        s += fmaxf(acc[mt][r], 0.f) * we2v[mt * 16 + r];
    s += __shfl_xor(s, 32);
    if (half == 0) out[t * 32 + n] = s + be2v;
  };

  for (int t = wid; t < ntiles; t += 2 * nw) {
    body(t, bufA, bufB);
    body(t + nw, bufB, bufA);
  }
}

extern "C" void kernel_launch(void* const* d_in, const int* in_sizes, int n_in,
                              void* d_out, int out_size, void* d_ws,
                              size_t ws_size, hipStream_t stream) {
  const float* X = (const float*)d_in[0];
  const int* pairs = (const int*)d_in[1];
  const float* W1 = (const float*)d_in[2];
  const float* b1 = (const float*)d_in[3];
  const float* W2 = (const float*)d_in[4];
  const float* b2 = (const float*)d_in[5];
  const float* We1 = (const float*)d_in[6];
  const float* be1 = (const float*)d_in[7];
  const float* We2 = (const float*)d_in[8];
  const float* be2 = (const float*)d_in[9];
  float* out = (float*)d_out;
  unsigned short* H = (unsigned short*)d_ws;  // 100000*64 bf16 = 12.8 MB

  node_mfma_kernel<<<1024, 64, 0, stream>>>(X, W1, b1, W2, b2, H);
  // 512 = 2 blocks/CU (65 KB LDS each): 8 waves/CU, 2 waves/SIMD.
  edge_mlp_kernel<<<512, 256, 0, stream>>>(H, pairs, We1, be1, We2, be2, out);
}